// Round 1
// baseline (1141.825 us; speedup 1.0000x reference)
//
#include <hip/hip_runtime.h>

// Problem constants
#define BATCH 8
#define LSEQ  1024
#define DMODEL 1024
#define NHEAD 16
#define DK 64
#define DV 64

typedef __bf16 bf16x8 __attribute__((ext_vector_type(8)));
typedef float  f32x4  __attribute__((ext_vector_type(4)));

static __device__ __forceinline__ unsigned short f2bf(float f) {
    union { float f; unsigned u; } x; x.f = f;
    unsigned r = x.u + 0x7FFFu + ((x.u >> 16) & 1u);   // RNE
    return (unsigned short)(r >> 16);
}
static __device__ __forceinline__ unsigned pack2(float lo, float hi) {
    return (unsigned)f2bf(lo) | ((unsigned)f2bf(hi) << 16);
}
static __device__ __forceinline__ f32x4 mfma16(bf16x8 a, bf16x8 b, f32x4 c) {
    return __builtin_amdgcn_mfma_f32_16x16x32_bf16(a, b, c, 0, 0, 0);
}
// XOR-swizzled 16B slot store/load into a [64][128B] (or [16][128B]) LDS tile.
static __device__ __forceinline__ void st_swz16(char* lds, int row, int slot, uint4 val) {
    *(uint4*)(lds + row * 128 + ((slot ^ (row & 7)) << 4)) = val;
}
static __device__ __forceinline__ bf16x8 ld_frag(const char* lds, int row, int slot) {
    return *(const bf16x8*)(lds + row * 128 + ((slot ^ (row & 7)) << 4));
}
// Stage a 64x64 fp32 tile -> bf16 swizzled LDS tile. 256 threads.
static __device__ __forceinline__ void stage_f32(const float* src, long ld, int row0, int col0,
                                                 char* lds, int t) {
    int row = t >> 2, cs = t & 3;
    const float4* p = (const float4*)(src + (long)(row0 + row) * ld + col0 + cs * 16);
    float4 a = p[0], b = p[1], c = p[2], d = p[3];
    uint4 u0 = { pack2(a.x, a.y), pack2(a.z, a.w), pack2(b.x, b.y), pack2(b.z, b.w) };
    uint4 u1 = { pack2(c.x, c.y), pack2(c.z, c.w), pack2(d.x, d.y), pack2(d.z, d.w) };
    st_swz16(lds, row, cs * 2, u0);
    st_swz16(lds, row, cs * 2 + 1, u1);
}
// Stage a 64x64 bf16 tile -> swizzled LDS tile. 256 threads.
static __device__ __forceinline__ void stage_bf16(const unsigned short* src, long ld, int row0,
                                                  int col0, char* lds, int t) {
    int row = t >> 2, cs = t & 3;
    const uint4* p = (const uint4*)(src + (long)(row0 + row) * ld + col0 + cs * 16);
    uint4 u0 = p[0], u1 = p[1];
    st_swz16(lds, row, cs * 2, u0);
    st_swz16(lds, row, cs * 2 + 1, u1);
}

// ---------------- mask dtype detection + bit packing ----------------
// If mask is 1-byte (bool), bytes at offset %4==1 are independent elements: ~10% nonzero.
// If 4-byte (int32 0/1 or float 0/1.0f), byte %4==1 is always 0.
__global__ void detect_mask_kernel(const unsigned char* mask, unsigned* flag) {
    __shared__ int cnt;
    if (threadIdx.x == 0) cnt = 0;
    __syncthreads();
    int any = 0;
    for (int i = threadIdx.x; i < 16384; i += 256) any |= (mask[4 * i + 1] != 0);
    if (any) atomicAdd(&cnt, 1);
    __syncthreads();
    if (threadIdx.x == 0) *flag = (cnt > 0) ? 1u : 0u;
}

// Pack mask -> bitmask: word w covers (b,q, k in [kw*32, kw*32+32)). bit j = masked.
__global__ __launch_bounds__(256) void pack_mask_kernel(const void* mask, const unsigned* flag,
                                                        unsigned* bits) {
    long w = (long)blockIdx.x * 256 + threadIdx.x;  // 262144 words
    unsigned m = 0;
    if (*flag) {  // 1-byte elements
        const uint4* p = (const uint4*)((const unsigned char*)mask + w * 32);
        uint4 a = p[0], b = p[1];
        unsigned arr[8] = { a.x, a.y, a.z, a.w, b.x, b.y, b.z, b.w };
#pragma unroll
        for (int i = 0; i < 8; ++i)
#pragma unroll
            for (int j = 0; j < 4; ++j)
                if ((arr[i] >> (8 * j)) & 0xFFu) m |= 1u << (i * 4 + j);
    } else {  // 4-byte elements (int32 or float: nonzero bits == masked)
        const uint4* p = (const uint4*)((const unsigned*)mask + w * 32);
#pragma unroll
        for (int i = 0; i < 8; ++i) {
            uint4 a = p[i];
            if (a.x) m |= 1u << (i * 4 + 0);
            if (a.y) m |= 1u << (i * 4 + 1);
            if (a.z) m |= 1u << (i * 4 + 2);
            if (a.w) m |= 1u << (i * 4 + 3);
        }
    }
    bits[w] = m;
}

// ---------------- projection GEMMs: qh/kh ([bh][L][64]) and v transposed ([bh][64][L]) ----------
__global__ __launch_bounds__(256) void proj_kernel(
    const float* __restrict__ qf, const float* __restrict__ kf, const float* __restrict__ vf,
    const float* __restrict__ wq, const float* __restrict__ wk, const float* __restrict__ wv,
    unsigned short* __restrict__ qh, unsigned short* __restrict__ kh,
    unsigned short* __restrict__ vt) {
    __shared__ char At[8192];
    __shared__ char Bt[8192];
    int z = blockIdx.z;
    const float* A = (z == 0) ? qf : (z == 1) ? kf : vf;
    const float* W = (z == 0) ? wq : (z == 1) ? wk : wv;
    int m0 = blockIdx.x * 64;
    int h = blockIdx.y;  // BN=64 == DK, so the N-tile IS one head
    int t = threadIdx.x, lane = t & 63, wid = t >> 6;
    int wm = wid >> 1, wn = wid & 1, lr = lane & 15, lg = lane >> 4;
    f32x4 acc[2][2];
#pragma unroll
    for (int i = 0; i < 2; ++i)
#pragma unroll
        for (int j = 0; j < 2; ++j) acc[i][j] = (f32x4){0.f, 0.f, 0.f, 0.f};

    for (int kb = 0; kb < 16; ++kb) {
        stage_f32(A, DMODEL, m0, kb * 64, At, t);
        stage_f32(W, DMODEL, h * 64, kb * 64, Bt, t);
        __syncthreads();
#pragma unroll
        for (int ks = 0; ks < 2; ++ks) {
            bf16x8 a0 = ld_frag(At, wm * 32 + lr, ks * 4 + lg);
            bf16x8 a1 = ld_frag(At, wm * 32 + 16 + lr, ks * 4 + lg);
            bf16x8 b0 = ld_frag(Bt, wn * 32 + lr, ks * 4 + lg);
            bf16x8 b1 = ld_frag(Bt, wn * 32 + 16 + lr, ks * 4 + lg);
            acc[0][0] = mfma16(a0, b0, acc[0][0]);
            acc[0][1] = mfma16(a0, b1, acc[0][1]);
            acc[1][0] = mfma16(a1, b0, acc[1][0]);
            acc[1][1] = mfma16(a1, b1, acc[1][1]);
        }
        __syncthreads();
    }
    int b = m0 >> 10;
    long bh = (long)b * NHEAD + h;
    if (z < 2) {
        unsigned short* dst = (z == 0) ? qh : kh;
#pragma unroll
        for (int mt = 0; mt < 2; ++mt)
#pragma unroll
            for (int nt = 0; nt < 2; ++nt)
#pragma unroll
                for (int r = 0; r < 4; ++r) {
                    int lq = (m0 & 1023) + wm * 32 + mt * 16 + lg * 4 + r;
                    int c = wn * 32 + nt * 16 + lr;
                    dst[(bh * LSEQ + lq) * 64 + c] = f2bf(acc[mt][nt][r]);
                }
    } else {
#pragma unroll
        for (int mt = 0; mt < 2; ++mt)
#pragma unroll
            for (int nt = 0; nt < 2; ++nt) {
                int lq = (m0 & 1023) + wm * 32 + mt * 16 + lg * 4;
                int c = wn * 32 + nt * 16 + lr;
                uint2 u;
                u.x = pack2(acc[mt][nt][0], acc[mt][nt][1]);
                u.y = pack2(acc[mt][nt][2], acc[mt][nt][3]);
                *(uint2*)(vt + (bh * 64 + c) * LSEQ + lq) = u;
            }
    }
}

// ---------------- fused attention: QK^T -> masked softmax (2-pass) -> write attn -> P.V --------
__global__ __launch_bounds__(256) void attn_kernel(
    const unsigned short* __restrict__ qh, const unsigned short* __restrict__ kh,
    const unsigned short* __restrict__ vt, const unsigned* __restrict__ mbits,
    float* __restrict__ attn, unsigned short* __restrict__ outb) {
    __shared__ char Kt[8192];
    __shared__ char Vts[8192];
    __shared__ char Pl[4][2048];
    int t = threadIdx.x, lane = t & 63, wid = t >> 6;
    int lr = lane & 15, lg = lane >> 4;
    int bh = blockIdx.y, b = bh >> 4, h = bh & 15;
    int q0 = blockIdx.x * 64 + wid * 16;  // 16 q-rows per wave
    const unsigned short* qb = qh + (long)bh * (LSEQ * 64);
    const unsigned short* khp = kh + (long)bh * (LSEQ * 64);
    const unsigned short* vb = vt + (long)bh * (64 * LSEQ);

    bf16x8 qa0, qa1;
    {
        const uint4* qp = (const uint4*)(qb + (long)(q0 + lr) * 64);
        qa0 = __builtin_bit_cast(bf16x8, qp[lg]);
        qa1 = __builtin_bit_cast(bf16x8, qp[4 + lg]);
    }
    float mM[4], lS[4];
#pragma unroll
    for (int r = 0; r < 4; ++r) { mM[r] = -3e38f; lS[r] = 0.f; }

    // ---- pass 1: row max + denom (online) ----
    for (int kb = 0; kb < 16; ++kb) {
        stage_bf16(khp, 64, kb * 64, 0, Kt, t);
        __syncthreads();
        unsigned long long mw[4];
#pragma unroll
        for (int r = 0; r < 4; ++r) {
            int qq = q0 + lg * 4 + r;
            uint2 ww = *(const uint2*)(mbits + (long)(b * LSEQ + qq) * 32 + kb * 2);
            mw[r] = (unsigned long long)ww.x | ((unsigned long long)ww.y << 32);
        }
#pragma unroll
        for (int t4 = 0; t4 < 4; ++t4) {
            int rk = t4 * 16 + lr;
            bf16x8 k0 = ld_frag(Kt, rk, lg);
            bf16x8 k1 = ld_frag(Kt, rk, 4 + lg);
            f32x4 d = (f32x4){0.f, 0.f, 0.f, 0.f};
            d = mfma16(qa0, k0, d);
            d = mfma16(qa1, k1, d);
#pragma unroll
            for (int r = 0; r < 4; ++r) {
                float s = d[r] * 0.125f;
                if ((mw[r] >> (t4 * 16 + lr)) & 1ull) s = -1e10f;
                float sm = s;
                sm = fmaxf(sm, __shfl_xor(sm, 1));
                sm = fmaxf(sm, __shfl_xor(sm, 2));
                sm = fmaxf(sm, __shfl_xor(sm, 4));
                sm = fmaxf(sm, __shfl_xor(sm, 8));
                float mn = fmaxf(mM[r], sm);
                float p = __expf(s - mn);
                p += __shfl_xor(p, 1);
                p += __shfl_xor(p, 2);
                p += __shfl_xor(p, 4);
                p += __shfl_xor(p, 8);
                lS[r] = lS[r] * __expf(mM[r] - mn) + p;
                mM[r] = mn;
            }
        }
        __syncthreads();
    }
    float invl[4];
#pragma unroll
    for (int r = 0; r < 4; ++r) invl[r] = 1.0f / lS[r];

    f32x4 accO[4];
#pragma unroll
    for (int d = 0; d < 4; ++d) accO[d] = (f32x4){0.f, 0.f, 0.f, 0.f};
    float* ab = attn + (long)(h * BATCH + b) * (LSEQ * LSEQ);

    // ---- pass 2: recompute, normalize, write attn, P.V ----
    for (int kb = 0; kb < 16; ++kb) {
        stage_bf16(khp, 64, kb * 64, 0, Kt, t);
        stage_bf16(vb, LSEQ, 0, kb * 64, Vts, t);
        __syncthreads();
        unsigned long long mw[4];
#pragma unroll
        for (int r = 0; r < 4; ++r) {
            int qq = q0 + lg * 4 + r;
            uint2 ww = *(const uint2*)(mbits + (long)(b * LSEQ + qq) * 32 + kb * 2);
            mw[r] = (unsigned long long)ww.x | ((unsigned long long)ww.y << 32);
        }
#pragma unroll
        for (int t4 = 0; t4 < 4; ++t4) {
            int rk = t4 * 16 + lr;
            bf16x8 k0 = ld_frag(Kt, rk, lg);
            bf16x8 k1 = ld_frag(Kt, rk, 4 + lg);
            f32x4 d = (f32x4){0.f, 0.f, 0.f, 0.f};
            d = mfma16(qa0, k0, d);
            d = mfma16(qa1, k1, d);
#pragma unroll
            for (int r = 0; r < 4; ++r) {
                float s = d[r] * 0.125f;
                if ((mw[r] >> (t4 * 16 + lr)) & 1ull) s = -1e10f;
                float p = __expf(s - mM[r]) * invl[r];
                int prow = lg * 4 + r;
                ab[(long)(q0 + prow) * LSEQ + kb * 64 + t4 * 16 + lr] = p;
                int slot = t4 * 2 + (lr >> 3);
                *(unsigned short*)(Pl[wid] + prow * 128 + ((slot ^ (prow & 7)) << 4) +
                                   (lr & 7) * 2) = f2bf(p);
            }
        }
        // P (A-operand) frags: row = q-local (lr), k-elems lg*8..
        bf16x8 pa0 = ld_frag(Pl[wid], lr, lg);
        bf16x8 pa1 = ld_frag(Pl[wid], lr, 4 + lg);
#pragma unroll
        for (int dv = 0; dv < 4; ++dv) {
            int rv = dv * 16 + lr;
            bf16x8 v0 = ld_frag(Vts, rv, lg);
            bf16x8 v1 = ld_frag(Vts, rv, 4 + lg);
            accO[dv] = mfma16(pa0, v0, accO[dv]);
            accO[dv] = mfma16(pa1, v1, accO[dv]);
        }
        __syncthreads();
    }
#pragma unroll
    for (int dv = 0; dv < 4; ++dv)
#pragma unroll
        for (int r = 0; r < 4; ++r) {
            long row = (long)b * LSEQ + q0 + lg * 4 + r;
            outb[row * DMODEL + h * 64 + dv * 16 + lr] = f2bf(accO[dv][r]);
        }
}

// ---------------- fc GEMM + bias + residual -> x (fp32, into d_out y region) ----------------
__global__ __launch_bounds__(256) void fc_kernel(const unsigned short* __restrict__ Ao,
                                                 const float* __restrict__ fw,
                                                 const float* __restrict__ fb,
                                                 const float* __restrict__ resid,
                                                 float* __restrict__ xout) {
    __shared__ char At[8192];
    __shared__ char Bt[8192];
    int m0 = blockIdx.x * 64, n0 = blockIdx.y * 64;
    int t = threadIdx.x, lane = t & 63, wid = t >> 6;
    int wm = wid >> 1, wn = wid & 1, lr = lane & 15, lg = lane >> 4;
    f32x4 acc[2][2];
#pragma unroll
    for (int i = 0; i < 2; ++i)
#pragma unroll
        for (int j = 0; j < 2; ++j) acc[i][j] = (f32x4){0.f, 0.f, 0.f, 0.f};

    for (int kb = 0; kb < 16; ++kb) {
        stage_bf16(Ao, DMODEL, m0, kb * 64, At, t);
        stage_f32(fw, DMODEL, n0, kb * 64, Bt, t);
        __syncthreads();
#pragma unroll
        for (int ks = 0; ks < 2; ++ks) {
            bf16x8 a0 = ld_frag(At, wm * 32 + lr, ks * 4 + lg);
            bf16x8 a1 = ld_frag(At, wm * 32 + 16 + lr, ks * 4 + lg);
            bf16x8 b0 = ld_frag(Bt, wn * 32 + lr, ks * 4 + lg);
            bf16x8 b1 = ld_frag(Bt, wn * 32 + 16 + lr, ks * 4 + lg);
            acc[0][0] = mfma16(a0, b0, acc[0][0]);
            acc[0][1] = mfma16(a0, b1, acc[0][1]);
            acc[1][0] = mfma16(a1, b0, acc[1][0]);
            acc[1][1] = mfma16(a1, b1, acc[1][1]);
        }
        __syncthreads();
    }
#pragma unroll
    for (int nt = 0; nt < 2; ++nt) {
        int n = n0 + wn * 32 + nt * 16 + lr;
        float fbv = fb[n];
#pragma unroll
        for (int mt = 0; mt < 2; ++mt)
#pragma unroll
            for (int r = 0; r < 4; ++r) {
                long m = m0 + wm * 32 + mt * 16 + lg * 4 + r;
                xout[m * DMODEL + n] = acc[mt][nt][r] + fbv + resid[m * DMODEL + n];
            }
    }
}

// ---------------- LayerNorm (in-place on x rows) ----------------
__global__ __launch_bounds__(256) void ln_kernel(float* __restrict__ x,
                                                 const float* __restrict__ g,
                                                 const float* __restrict__ bb) {
    int row = blockIdx.x, t = threadIdx.x;
    float4* p = (float4*)(x + (long)row * DMODEL);
    float4 v = p[t];
    float s = v.x + v.y + v.z + v.w;
    float sq = v.x * v.x + v.y * v.y + v.z * v.z + v.w * v.w;
#pragma unroll
    for (int o = 1; o < 64; o <<= 1) {
        s += __shfl_xor(s, o);
        sq += __shfl_xor(sq, o);
    }
    __shared__ float red[8];
    int wid = t >> 6, lane = t & 63;
    if (lane == 0) { red[wid] = s; red[4 + wid] = sq; }
    __syncthreads();
    s = red[0] + red[1] + red[2] + red[3];
    sq = red[4] + red[5] + red[6] + red[7];
    float mu = s * (1.f / 1024.f);
    float var = sq * (1.f / 1024.f) - mu * mu;
    float rs = rsqrtf(var + 1e-5f);
    const float4 gv = ((const float4*)g)[t];
    const float4 bv = ((const float4*)bb)[t];
    float4 o;
    o.x = (v.x - mu) * rs * gv.x + bv.x;
    o.y = (v.y - mu) * rs * gv.y + bv.y;
    o.z = (v.z - mu) * rs * gv.z + bv.z;
    o.w = (v.w - mu) * rs * gv.w + bv.w;
    p[t] = o;
}

extern "C" void kernel_launch(void* const* d_in, const int* in_sizes, int n_in,
                              void* d_out, int out_size, void* d_ws, size_t ws_size,
                              hipStream_t stream) {
    const float* q = (const float*)d_in[0];
    const float* k = (const float*)d_in[1];
    const float* v = (const float*)d_in[2];
    const void* mask = d_in[3];
    const float* wq = (const float*)d_in[4];
    const float* wk = (const float*)d_in[5];
    const float* wv = (const float*)d_in[6];
    const float* fw = (const float*)d_in[7];
    const float* fb = (const float*)d_in[8];
    const float* lgm = (const float*)d_in[9];
    const float* lbt = (const float*)d_in[10];

    char* ws = (char*)d_ws;
    unsigned* flag = (unsigned*)ws;                       // 4 B
    unsigned* bits = (unsigned*)(ws + 1024);              // 1 MiB bitmask
    unsigned short* qhB = (unsigned short*)(ws + (1u << 21));  // 16 MiB [bh][L][64]
    unsigned short* khB = qhB + 8388608;                  // 16 MiB [bh][L][64]
    unsigned short* vtB = khB + 8388608;                  // 16 MiB [bh][64][L] (transposed)
    unsigned short* outB = vtB + 8388608;                 // 16 MiB [B*L][H*DV]

    float* y = (float*)d_out;                             // [B*L][D] (x then LN'd in place)
    float* attn = y + 8388608;                            // [H*B][L][L]

    detect_mask_kernel<<<dim3(1), dim3(256), 0, stream>>>((const unsigned char*)mask, flag);
    pack_mask_kernel<<<dim3(1024), dim3(256), 0, stream>>>(mask, flag, bits);
    proj_kernel<<<dim3(128, 16, 3), dim3(256), 0, stream>>>(q, k, v, wq, wk, wv, qhB, khB, vtB);
    attn_kernel<<<dim3(16, 128), dim3(256), 0, stream>>>(qhB, khB, vtB, bits, attn, outB);
    fc_kernel<<<dim3(128, 16), dim3(256), 0, stream>>>(outB, fw, fb, q, y);
    ln_kernel<<<dim3(8192), dim3(256), 0, stream>>>(y, lgm, lbt);
}